// Round 13
// baseline (85.485 us; speedup 1.0000x reference)
//
#include <hip/hip_runtime.h>

#define TWO_LOG2E 2.8853901817779268f   // 2*log2(e)
#define LOG2E     1.4426950408889634f

typedef float f32x2 __attribute__((ext_vector_type(2)));
typedef float f32x4 __attribute__((ext_vector_type(4)));

__device__ __forceinline__ f32x2 splat2(float s) { f32x2 v; v.x = s; v.y = s; return v; }

// THREAD = EDGE (viable now that weights live in LDS — R8's failure was the
// SGPR reload path, not the layout). Vs quad layout: idx loads not 4x-redundant,
// one f32x4 store per edge, no DPP softmax, half the vmem instructions, and
// half the vmcnt stall exposures per unit work. Class loop OUTSIDE edge batch
// so weight ds_reads (uniform broadcast, conflict-free) amortize over 4 edges.
__global__ __launch_bounds__(256, 2) void edge_mlp(
    const float* __restrict__ m,     // [N_NODES, 4, 2]
    const int*   __restrict__ eidx,  // [2, E]
    const float* __restrict__ W1,    // [4, 4, 8]
    const float* __restrict__ b1,    // [4, 8]
    const float* __restrict__ W2,    // [4, 8, 1]
    const float* __restrict__ b2,    // [4, 1]
    float*       __restrict__ out,   // [E, 4]
    const int nE)
{
    // R12's prescaled pair layout (padding kept; reads are uniform broadcasts).
    __shared__ __align__(16) float sw1[4 * 36]; // [c][p][i][01]=W1[c][i][2p+?]*2log2e
    __shared__ __align__(16) float sbw[4 * 18]; // [c][p]={b1 pair, -2*2log2e*W2 pair}
    __shared__ float so0[4];                    // 2log2e*(b2[c] + sum_j W2[c][j])

    const int tidb = threadIdx.x;
    if (tidb < 128) {
        const int c = tidb >> 5, r = tidb & 31, i = r >> 3, j = r & 7;
        sw1[c * 36 + (j >> 1) * 8 + i * 2 + (j & 1)] =
            W1[c * 32 + i * 8 + j] * TWO_LOG2E;
    } else if (tidb < 192) {
        const int q = tidb - 128, c = q >> 4, r = q & 15, p = r >> 2, k = r & 3;
        const int j = 2 * p + (k & 1);
        sbw[c * 18 + p * 4 + k] =
            (k < 2) ? b1[c * 8 + j] * TWO_LOG2E
                    : W2[c * 8 + j] * (-2.0f * TWO_LOG2E);
    } else if (tidb < 196) {
        const int c = tidb - 192;
        float s = b2[c];
        #pragma unroll
        for (int j = 0; j < 8; ++j) s += W2[c * 8 + j];
        so0[c] = s * TWO_LOG2E;
    }
    __syncthreads();

    float o0r[4];
    #pragma unroll
    for (int c = 0; c < 4; ++c) o0r[c] = so0[c];

    const int tid    = blockIdx.x * blockDim.x + threadIdx.x;
    const int stride = gridDim.x * blockDim.x;
    const int* eidx1 = eidx + nE;
    constexpr int UN = 4;

    int e = tid;
    for (; e + (UN - 1) * stride < nE; e += UN * stride) {
        int ri[UN], ci[UN];
        #pragma unroll
        for (int k = 0; k < UN; ++k) {
            ri[k] = __builtin_nontemporal_load(eidx  + e + k * stride);
            ci[k] = __builtin_nontemporal_load(eidx1 + e + k * stride);
        }
        f32x4 A[UN], B[UN], C[UN], D[UN];   // col lo/hi, row lo/hi (32B rows)
        #pragma unroll
        for (int k = 0; k < UN; ++k) {
            const unsigned co = (unsigned)ci[k] * 8u, ro = (unsigned)ri[k] * 8u;
            A[k] = *(const f32x4*)(m + co);  B[k] = *(const f32x4*)(m + co + 4);
            C[k] = *(const f32x4*)(m + ro);  D[k] = *(const f32x4*)(m + ro + 4);
        }

        float eo[UN][4], ss[UN];
        #pragma unroll
        for (int k = 0; k < UN; ++k) ss[k] = 0.0f;

        #pragma unroll
        for (int c = 0; c < 4; ++c) {       // class outer: weights amortized
            const float* w1c = sw1 + c * 36;
            const f32x2* bwc = (const f32x2*)(sbw + c * 18);
            float o[UN];
            #pragma unroll
            for (int k = 0; k < UN; ++k) o[k] = o0r[c];
            #pragma unroll
            for (int p = 0; p < 4; ++p) {   // j-pair
                const f32x2* wp   = (const f32x2*)(w1c + p * 8);
                const f32x2 bb01  = bwc[p * 2];
                const f32x2 w2n01 = bwc[p * 2 + 1];
                #pragma unroll
                for (int k = 0; k < UN; ++k) {
                    const f32x4 lo = (c < 2) ? A[k] : B[k];
                    const f32x4 rr = (c < 2) ? C[k] : D[k];
                    const float mx = (c & 1) ? lo.z : lo.x;
                    const float my = (c & 1) ? lo.w : lo.y;
                    const float rx = (c & 1) ? rr.z : rr.x;
                    const float ry = (c & 1) ? rr.w : rr.y;
                    f32x2 h = bb01;
                    h = __builtin_elementwise_fma(splat2(mx), wp[0], h);
                    h = __builtin_elementwise_fma(splat2(my), wp[1], h);
                    h = __builtin_elementwise_fma(splat2(rx), wp[2], h);
                    h = __builtin_elementwise_fma(splat2(ry), wp[3], h);
                    const float a0 = __builtin_amdgcn_exp2f(h.x) + 1.0f;
                    const float a1 = __builtin_amdgcn_exp2f(h.y) + 1.0f;
                    const float inv = __builtin_amdgcn_rcpf(a0 * a1);
                    o[k] = fmaf(w2n01.x, inv * a1, o[k]);
                    o[k] = fmaf(w2n01.y, inv * a0, o[k]);
                }
            }
            #pragma unroll
            for (int k = 0; k < UN; ++k) {
                const float e2 = __builtin_amdgcn_exp2f(o[k]);
                const float r2 = __builtin_amdgcn_rcpf(e2 + 1.0f);
                const float v  = __builtin_amdgcn_exp2f(fmaf(-TWO_LOG2E, r2, LOG2E));
                eo[k][c] = v;
                ss[k] += v;
            }
        }
        #pragma unroll
        for (int k = 0; k < UN; ++k) {
            const float rs = __builtin_amdgcn_rcpf(ss[k]);
            f32x4 res;
            res.x = eo[k][0] * rs; res.y = eo[k][1] * rs;
            res.z = eo[k][2] * rs; res.w = eo[k][3] * rs;
            __builtin_nontemporal_store(res,
                reinterpret_cast<f32x4*>(out) + (e + k * stride));
        }
    }

    // tail: one edge at a time
    for (; e < nE; e += stride) {
        const int r0 = eidx[e];
        const int c0 = eidx1[e];
        const unsigned co = (unsigned)c0 * 8u, ro = (unsigned)r0 * 8u;
        const f32x4 A0 = *(const f32x4*)(m + co), B0 = *(const f32x4*)(m + co + 4);
        const f32x4 C0 = *(const f32x4*)(m + ro), D0 = *(const f32x4*)(m + ro + 4);
        float eo[4], ss = 0.0f;
        #pragma unroll
        for (int c = 0; c < 4; ++c) {
            const float* w1c = sw1 + c * 36;
            const f32x2* bwc = (const f32x2*)(sbw + c * 18);
            const f32x4 lo = (c < 2) ? A0 : B0;
            const f32x4 rr = (c < 2) ? C0 : D0;
            const float mx = (c & 1) ? lo.z : lo.x;
            const float my = (c & 1) ? lo.w : lo.y;
            const float rx = (c & 1) ? rr.z : rr.x;
            const float ry = (c & 1) ? rr.w : rr.y;
            float o = o0r[c];
            #pragma unroll
            for (int p = 0; p < 4; ++p) {
                const f32x2* wp   = (const f32x2*)(w1c + p * 8);
                const f32x2 bb01  = bwc[p * 2];
                const f32x2 w2n01 = bwc[p * 2 + 1];
                f32x2 h = bb01;
                h = __builtin_elementwise_fma(splat2(mx), wp[0], h);
                h = __builtin_elementwise_fma(splat2(my), wp[1], h);
                h = __builtin_elementwise_fma(splat2(rx), wp[2], h);
                h = __builtin_elementwise_fma(splat2(ry), wp[3], h);
                const float a0 = __builtin_amdgcn_exp2f(h.x) + 1.0f;
                const float a1 = __builtin_amdgcn_exp2f(h.y) + 1.0f;
                const float inv = __builtin_amdgcn_rcpf(a0 * a1);
                o = fmaf(w2n01.x, inv * a1, o);
                o = fmaf(w2n01.y, inv * a0, o);
            }
            const float e2 = __builtin_amdgcn_exp2f(o);
            const float r2 = __builtin_amdgcn_rcpf(e2 + 1.0f);
            eo[c] = __builtin_amdgcn_exp2f(fmaf(-TWO_LOG2E, r2, LOG2E));
            ss += eo[c];
        }
        const float rs = __builtin_amdgcn_rcpf(ss);
        f32x4 res;
        res.x = eo[0] * rs; res.y = eo[1] * rs;
        res.z = eo[2] * rs; res.w = eo[3] * rs;
        __builtin_nontemporal_store(res, reinterpret_cast<f32x4*>(out) + e);
    }
}

extern "C" void kernel_launch(void* const* d_in, const int* in_sizes, int n_in,
                              void* d_out, int out_size, void* d_ws, size_t ws_size,
                              hipStream_t stream) {
    const float* m  = (const float*)d_in[0];
    const int* eidx = (const int*)d_in[1];
    const float* W1 = (const float*)d_in[2];
    const float* b1 = (const float*)d_in[3];
    const float* W2 = (const float*)d_in[4];
    const float* b2 = (const float*)d_in[5];
    float* out = (float*)d_out;
    const int nE = in_sizes[1] / 2;   // 3.2M edges

    const int threads = 256;
    const int blocks  = 1536;         // ~8 edges/thread: 2 batched iters + tail
    hipLaunchKernelGGL(edge_mlp, dim3(blocks), dim3(threads), 0, stream,
                       m, eidx, W1, b1, W2, b2, out, nE);
}

// Round 14
// 55.685 us; speedup vs baseline: 1.5351x; 1.5351x over previous
//
#include <hip/hip_runtime.h>

#define TWO_LOG2E 2.8853901817779268f   // 2*log2(e)
#define LOG2E     1.4426950408889634f

typedef float f32x2 __attribute__((ext_vector_type(2)));

// quad_perm DPP cross-lane (VALU pipe)
template<int CTRL>
__device__ __forceinline__ float dpp_qperm(float x) {
    int r = __builtin_amdgcn_update_dpp(0, __float_as_int(x), CTRL, 0xF, 0xF, true);
    return __int_as_float(r);
}

__device__ __forceinline__ f32x2 splat2(float s) { f32x2 v; v.x = s; v.y = s; return v; }

// R12 (best, 54.8us) + wave-phase STAGGER: all waves start in lockstep with
// identical compute-phase lengths, so their gather vmcnt-waits align and no
// wave has compute to cover another's stall. s_sleep((wid&7)*64cyc) at entry
// spreads phases across ~one gather round-trip. Keep <=64 VGPR (R13: crossing
// 64 halves waves/CU).
__global__ void edge_mlp(
    const float* __restrict__ m,     // [N_NODES, 4, 2]
    const int*   __restrict__ eidx,  // [2, E]
    const float* __restrict__ W1,    // [4, 4, 8]
    const float* __restrict__ b1,    // [4, 8]
    const float* __restrict__ W2,    // [4, 8, 1]
    const float* __restrict__ b2,    // [4, 1]
    float*       __restrict__ out,   // [E, 4]
    const int nE)
{
    __shared__ __align__(16) float sw1[4 * 36]; // [c][p][i][01]=W1[c][i][2p+?]*2log2e
    __shared__ __align__(16) float sbw[4 * 18]; // [c][p]={b1 pair, -2*2log2e*W2 pair}
    __shared__ float so0[4];                    // 2log2e*(b2[c] + sum_j W2[c][j])

    const int tidb = threadIdx.x;
    if (tidb < 128) {
        const int c = tidb >> 5, r = tidb & 31, i = r >> 3, j = r & 7;
        sw1[c * 36 + (j >> 1) * 8 + i * 2 + (j & 1)] =
            W1[c * 32 + i * 8 + j] * TWO_LOG2E;
    } else if (tidb < 192) {
        const int q = tidb - 128, c = q >> 4, r = q & 15, p = r >> 2, k = r & 3;
        const int j = 2 * p + (k & 1);
        sbw[c * 18 + p * 4 + k] =
            (k < 2) ? b1[c * 8 + j] * TWO_LOG2E
                    : W2[c * 8 + j] * (-2.0f * TWO_LOG2E);
    } else if (tidb < 196) {
        const int c = tidb - 192;
        float s = b2[c];
        #pragma unroll
        for (int j = 0; j < 8; ++j) s += W2[c * 8 + j];
        so0[c] = s * TWO_LOG2E;
    }
    __syncthreads();

    // ---- phase stagger: desync the waves of this CU ----
    switch ((threadIdx.x >> 6) ^ (blockIdx.x & 3)) {
        case 1: __builtin_amdgcn_s_sleep(2); break;   // ~128 cyc
        case 2: __builtin_amdgcn_s_sleep(4); break;   // ~256 cyc
        case 3: __builtin_amdgcn_s_sleep(6); break;   // ~384 cyc
        default: break;
    }

    const int tid0 = blockIdx.x * blockDim.x + threadIdx.x;
    const int c = tid0 & 3;
    const int cc2 = c * 2;
    const float* w1c = sw1 + c * 36;
    const f32x2* bwc = (const f32x2*)(sbw + c * 18);
    const float o0 = so0[c];

    const int* eidx1 = eidx + nE;
    const int total  = nE * 4;
    const int stride = gridDim.x * blockDim.x;   // multiple of 4 -> c constant

    constexpr int UN = 4;
    int t = tid0;

    for (; t + (UN - 1) * stride < total; t += UN * stride) {
        int row[UN], col[UN];
        #pragma unroll
        for (int k = 0; k < UN; ++k) {
            const int e = (t + k * stride) >> 2;
            row[k] = __builtin_nontemporal_load(eidx  + e);
            col[k] = __builtin_nontemporal_load(eidx1 + e);
        }
        f32x2 mc[UN], mr[UN];
        #pragma unroll
        for (int k = 0; k < UN; ++k) {
            mc[k] = *(const f32x2*)(m + (unsigned)col[k] * 8u + cc2);
            mr[k] = *(const f32x2*)(m + (unsigned)row[k] * 8u + cc2);
        }
        #pragma unroll
        for (int k = 0; k < UN; ++k) {
            float o = o0;                          // scaled domain (x 2log2e)
            #pragma unroll
            for (int p = 0; p < 4; ++p) {          // j-pair p: packed layer-1
                const f32x2* wp = (const f32x2*)(w1c + p * 8);
                f32x2 h = bwc[p * 2];              // bb01
                h = __builtin_elementwise_fma(splat2(mc[k].x), wp[0], h);
                h = __builtin_elementwise_fma(splat2(mc[k].y), wp[1], h);
                h = __builtin_elementwise_fma(splat2(mr[k].x), wp[2], h);
                h = __builtin_elementwise_fma(splat2(mr[k].y), wp[3], h);
                const float a0 = __builtin_amdgcn_exp2f(h.x) + 1.0f; // 1+e^{2x}
                const float a1 = __builtin_amdgcn_exp2f(h.y) + 1.0f;
                const float inv = __builtin_amdgcn_rcpf(a0 * a1);
                const f32x2 w2n01 = bwc[p * 2 + 1];
                o = fmaf(w2n01.x, inv * a1, o);    // tanh0 * w2_0 (folded)
                o = fmaf(w2n01.y, inv * a0, o);    // tanh1 * w2_1
            }
            const float e2 = __builtin_amdgcn_exp2f(o);
            const float r2 = __builtin_amdgcn_rcpf(e2 + 1.0f);
            // eo = e^{tanh(o_true)} = 2^{LOG2E - TWO_LOG2E*r2}
            const float eo = __builtin_amdgcn_exp2f(fmaf(-TWO_LOG2E, r2, LOG2E));
            float s = eo + dpp_qperm<0xB1>(eo);    // quad softmax denom
            s = s + dpp_qperm<0x4E>(s);
            __builtin_nontemporal_store(eo * __builtin_amdgcn_rcpf(s),
                                        out + (t + k * stride));
        }
    }

    // tail
    for (; t < total; t += stride) {
        const int e  = t >> 2;
        const int r0 = eidx[e];
        const int c0 = eidx1[e];
        const f32x2 mcv = *(const f32x2*)(m + (unsigned)c0 * 8u + cc2);
        const f32x2 mrv = *(const f32x2*)(m + (unsigned)r0 * 8u + cc2);
        float o = o0;
        #pragma unroll
        for (int p = 0; p < 4; ++p) {
            const f32x2* wp = (const f32x2*)(w1c + p * 8);
            f32x2 h = bwc[p * 2];
            h = __builtin_elementwise_fma(splat2(mcv.x), wp[0], h);
            h = __builtin_elementwise_fma(splat2(mcv.y), wp[1], h);
            h = __builtin_elementwise_fma(splat2(mrv.x), wp[2], h);
            h = __builtin_elementwise_fma(splat2(mrv.y), wp[3], h);
            const float a0 = __builtin_amdgcn_exp2f(h.x) + 1.0f;
            const float a1 = __builtin_amdgcn_exp2f(h.y) + 1.0f;
            const float inv = __builtin_amdgcn_rcpf(a0 * a1);
            const f32x2 w2n01 = bwc[p * 2 + 1];
            o = fmaf(w2n01.x, inv * a1, o);
            o = fmaf(w2n01.y, inv * a0, o);
        }
        const float e2 = __builtin_amdgcn_exp2f(o);
        const float r2 = __builtin_amdgcn_rcpf(e2 + 1.0f);
        const float eo = __builtin_amdgcn_exp2f(fmaf(-TWO_LOG2E, r2, LOG2E));
        float s = eo + dpp_qperm<0xB1>(eo);
        s = s + dpp_qperm<0x4E>(s);
        out[t] = eo * __builtin_amdgcn_rcpf(s);
    }
}

extern "C" void kernel_launch(void* const* d_in, const int* in_sizes, int n_in,
                              void* d_out, int out_size, void* d_ws, size_t ws_size,
                              hipStream_t stream) {
    const float* m  = (const float*)d_in[0];
    const int* eidx = (const int*)d_in[1];
    const float* W1 = (const float*)d_in[2];
    const float* b1 = (const float*)d_in[3];
    const float* W2 = (const float*)d_in[4];
    const float* b2 = (const float*)d_in[5];
    float* out = (float*)d_out;
    const int nE = in_sizes[1] / 2;

    const int threads = 256;
    const int blocks  = 2048;
    hipLaunchKernelGGL(edge_mlp, dim3(blocks), dim3(threads), 0, stream,
                       m, eidx, W1, b1, W2, b2, out, nE);
}